// Round 2
// baseline (86.949 us; speedup 1.0000x reference)
//
#include <hip/hip_runtime.h>

// BSplineActivation: y = sum_i B_i^3(clip(x,-1,1)) * c_i over a 12-knot
// uniform grid on [-1.2, 1.2]. GRID_SIZE=5, ORDER=3 -> 8 bases, 11 intervals.
// On interval j the result is a single cubic in u = (x - g0)/h - j:
//   y = A_j + B_j*u + C_j*u^2 + D_j*u^3
// Table (11 x float4) built once per block in LDS.
//
// MLP-focused revision:
//  - 2 float4-equivalents in flight per thread per iteration,
//  - software prefetch of the next pair before evaluating the current one,
//  - first global loads issued BEFORE the table build / __syncthreads,
//  - nontemporal loads/stores via native Clang ext-vector type
//    (HIP float4 is a struct and __builtin_nontemporal_* rejects it).

typedef float f4 __attribute__((ext_vector_type(4)));

__device__ __forceinline__ float eval1(float xv, float g0, float invh,
                                       const float4* __restrict__ table)
{
    float xc = fminf(fmaxf(xv, -1.0f), 1.0f);
    float t  = (xc - g0) * invh;        // grid-units position, ~[0.92, 10.09]
    int   j  = (int)t;                  // t >= 0 -> trunc == floor
    j = j < 0 ? 0 : (j > 10 ? 10 : j);
    float u  = t - (float)j;
    float4 p = table[j];                // ds_read_b128, <=2-way bank alias (free)
    return ((p.w * u + p.z) * u + p.y) * u + p.x;
}

__device__ __forceinline__ f4 eval4(f4 v, float g0, float invh,
                                    const float4* __restrict__ table)
{
    f4 r;
    r.x = eval1(v.x, g0, invh, table);
    r.y = eval1(v.y, g0, invh, table);
    r.z = eval1(v.z, g0, invh, table);
    r.w = eval1(v.w, g0, invh, table);
    return r;
}

__global__ void __launch_bounds__(256) bspline_act_kernel(
    const float* __restrict__ x,
    const float* __restrict__ grid,
    const float* __restrict__ coeff,
    float* __restrict__ out,
    int n4)
{
    __shared__ float4 table[11];
    __shared__ float s_g0, s_invh;

    const int tid = threadIdx.x;
    const f4* __restrict__ x4 = (const f4*)x;
    f4* __restrict__ o4 = (f4*)out;

    const int stride = gridDim.x * blockDim.x;      // total threads
    const int base   = blockIdx.x * blockDim.x + tid;

    // ---- issue the first pair of loads BEFORE touching LDS ----
    int i0 = base;
    int i1 = base + stride;
    bool va = i0 < n4;
    bool vb = i1 < n4;
    f4 a = {0.f, 0.f, 0.f, 0.f}, b = {0.f, 0.f, 0.f, 0.f};
    if (va) a = __builtin_nontemporal_load(&x4[i0]);
    if (vb) b = __builtin_nontemporal_load(&x4[i1]);

    if (tid == 0) {
        float g0  = grid[0];
        float g11 = grid[11];
        s_g0   = g0;
        s_invh = 11.0f / (g11 - g0);
    }
    if (tid < 11) {
        const int j = tid;
        float c[4];
#pragma unroll
        for (int m = 0; m < 4; ++m) {
            int idx = j + m - 3;              // basis index j-3+m
            c[m] = (idx >= 0 && idx < 8) ? coeff[idx] : 0.0f;
        }
        const float k6 = 1.0f / 6.0f;
        float A = (c[0] + 4.0f * c[1] + c[2]) * k6;
        float B = (3.0f * (c[2] - c[0])) * k6;
        float C = (3.0f * c[0] - 6.0f * c[1] + 3.0f * c[2]) * k6;
        float D = (-c[0] + 3.0f * c[1] - 3.0f * c[2] + c[3]) * k6;
        table[j] = make_float4(A, B, C, D);
    }
    __syncthreads();

    const float g0   = s_g0;
    const float invh = s_invh;

    // ---- main loop: prefetch next pair, then evaluate+store current ----
    while (va) {
        const int ni0 = i0 + 2 * stride;
        const int ni1 = i1 + 2 * stride;
        const bool vna = ni0 < n4;
        const bool vnb = ni1 < n4;
        f4 na = {0.f, 0.f, 0.f, 0.f}, nb = {0.f, 0.f, 0.f, 0.f};
        if (vna) na = __builtin_nontemporal_load(&x4[ni0]);
        if (vnb) nb = __builtin_nontemporal_load(&x4[ni1]);

        f4 ra = eval4(a, g0, invh, table);
        __builtin_nontemporal_store(ra, &o4[i0]);
        if (vb) {
            f4 rb = eval4(b, g0, invh, table);
            __builtin_nontemporal_store(rb, &o4[i1]);
        }

        i0 = ni0; i1 = ni1;
        a = na; b = nb;
        va = vna; vb = vnb;
    }
}

extern "C" void kernel_launch(void* const* d_in, const int* in_sizes, int n_in,
                              void* d_out, int out_size, void* d_ws, size_t ws_size,
                              hipStream_t stream) {
    const float* x     = (const float*)d_in[0];
    const float* grid  = (const float*)d_in[1];
    const float* coeff = (const float*)d_in[2];
    float* out = (float*)d_out;

    const int n  = in_sizes[0];          // 2048*4096 = 8388608, divisible by 4
    const int n4 = n >> 2;               // 2097152 float4 elements

    const int block = 256;
    const int blocks = 2048;             // 32 waves/CU; 2 pair-iterations/thread
    bspline_act_kernel<<<blocks, block, 0, stream>>>(x, grid, coeff, out, n4);
}

// Round 3
// 82.846 us; speedup vs baseline: 1.0495x; 1.0495x over previous
//
#include <hip/hip_runtime.h>

// BSplineActivation: y = sum_i B_i^3(clip(x,-1,1)) * c_i over a 12-knot
// uniform grid on [-1.2, 1.2]. GRID_SIZE=5, ORDER=3 -> 8 bases, 11 intervals.
// On interval j the result is a single cubic in u = (x - g0)/h - j:
//   y = A_j + B_j*u + C_j*u^2 + D_j*u^3
// Table (11 x float4) built once per block in LDS (<=2-way bank alias = free).
//
// Round-3 config:
//  - TEMPORAL loads (input is L3-resident across bench iterations; round-2's
//    nontemporal loads bypassed L3 and cost +3.3 us = HBM-vs-L3 on 33.5 MB),
//  - NONTEMPORAL stores only (output never re-read; don't evict input from L3),
//  - fast path: n4 == 4*stride exactly (2048 blocks x 256 thr x 4 float4),
//    fully unrolled, all 4 loads issued before the LDS table build ->
//    4 loads in flight/thread, zero loop/guard overhead. Generic fallback.

typedef float f4 __attribute__((ext_vector_type(4)));

__device__ __forceinline__ float eval1(float xv, float g0, float invh,
                                       const float4* __restrict__ table)
{
    float xc = fminf(fmaxf(xv, -1.0f), 1.0f);
    float t  = (xc - g0) * invh;        // grid-units position, ~[0.92, 10.09]
    int   j  = (int)t;                  // t >= 0 -> trunc == floor
    j = j < 0 ? 0 : (j > 10 ? 10 : j);
    float u  = t - (float)j;
    float4 p = table[j];                // ds_read_b128
    return ((p.w * u + p.z) * u + p.y) * u + p.x;
}

__device__ __forceinline__ f4 eval4(f4 v, float g0, float invh,
                                    const float4* __restrict__ table)
{
    f4 r;
    r.x = eval1(v.x, g0, invh, table);
    r.y = eval1(v.y, g0, invh, table);
    r.z = eval1(v.z, g0, invh, table);
    r.w = eval1(v.w, g0, invh, table);
    return r;
}

__global__ void __launch_bounds__(256) bspline_act_kernel(
    const float* __restrict__ x,
    const float* __restrict__ grid,
    const float* __restrict__ coeff,
    float* __restrict__ out,
    int n4)
{
    __shared__ float4 table[11];
    __shared__ float s_g0, s_invh;

    const int tid    = threadIdx.x;
    const int stride = gridDim.x * blockDim.x;
    const int base   = blockIdx.x * blockDim.x + tid;

    const f4* __restrict__ x4 = (const f4*)x;
    f4* __restrict__ o4 = (f4*)out;

    const bool fast = (n4 == (stride << 2));

    // ---- fast path: issue all 4 loads BEFORE the LDS table build ----
    f4 a0, a1, a2, a3;
    if (fast) {
        a0 = x4[base];
        a1 = x4[base +     stride];
        a2 = x4[base + 2 * stride];
        a3 = x4[base + 3 * stride];
    }

    if (tid == 0) {
        float g0  = grid[0];
        float g11 = grid[11];
        s_g0   = g0;
        s_invh = 11.0f / (g11 - g0);
    }
    if (tid < 11) {
        const int j = tid;
        float c[4];
#pragma unroll
        for (int m = 0; m < 4; ++m) {
            int idx = j + m - 3;              // basis index j-3+m
            c[m] = (idx >= 0 && idx < 8) ? coeff[idx] : 0.0f;
        }
        const float k6 = 1.0f / 6.0f;
        float A = (c[0] + 4.0f * c[1] + c[2]) * k6;
        float B = (3.0f * (c[2] - c[0])) * k6;
        float C = (3.0f * c[0] - 6.0f * c[1] + 3.0f * c[2]) * k6;
        float D = (-c[0] + 3.0f * c[1] - 3.0f * c[2] + c[3]) * k6;
        table[j] = make_float4(A, B, C, D);
    }
    __syncthreads();

    const float g0   = s_g0;
    const float invh = s_invh;

    if (fast) {
        f4 r0 = eval4(a0, g0, invh, table);
        __builtin_nontemporal_store(r0, &o4[base]);
        f4 r1 = eval4(a1, g0, invh, table);
        __builtin_nontemporal_store(r1, &o4[base +     stride]);
        f4 r2 = eval4(a2, g0, invh, table);
        __builtin_nontemporal_store(r2, &o4[base + 2 * stride]);
        f4 r3 = eval4(a3, g0, invh, table);
        __builtin_nontemporal_store(r3, &o4[base + 3 * stride]);
        return;
    }

    // ---- generic fallback ----
    for (int i = base; i < n4; i += stride) {
        f4 v = x4[i];
        f4 r = eval4(v, g0, invh, table);
        __builtin_nontemporal_store(r, &o4[i]);
    }
}

extern "C" void kernel_launch(void* const* d_in, const int* in_sizes, int n_in,
                              void* d_out, int out_size, void* d_ws, size_t ws_size,
                              hipStream_t stream) {
    const float* x     = (const float*)d_in[0];
    const float* grid  = (const float*)d_in[1];
    const float* coeff = (const float*)d_in[2];
    float* out = (float*)d_out;

    const int n  = in_sizes[0];          // 2048*4096 = 8388608, divisible by 4
    const int n4 = n >> 2;               // 2097152 float4 elements

    const int block = 256;
    const int blocks = 2048;             // 524288 threads -> exactly 4 f4/thread
    bspline_act_kernel<<<blocks, block, 0, stream>>>(x, grid, coeff, out, n4);
}